// Round 6
// baseline (1533.678 us; speedup 1.0000x reference)
//
#include <hip/hip_runtime.h>
#include <stdint.h>

typedef long long ll;
typedef unsigned short u16;
typedef __attribute__((ext_vector_type(8))) short bf16x8;
typedef __attribute__((ext_vector_type(4))) float f32x4;

// ---------- edge-index dtype detection (int64 vs int32, decided on device) ----------
__device__ inline bool ei_is64(const void* ei) {
  const int* p = (const int*)ei;
  return ((p[1] | p[3] | p[5] | p[7]) == 0);
}
__device__ inline int ei_at(const void* ei, ll i, bool is64) {
  return is64 ? (int)((const ll*)ei)[i] : ((const int*)ei)[i];
}

// ---------- helpers ----------
__device__ inline float fast_tanh(float x) {
  x = fminf(15.f, fmaxf(-15.f, x));
  float e2 = __expf(2.f * x);
  return (e2 - 1.f) / (e2 + 1.f);
}
__device__ inline float fast_sigmoid(float x) { return 1.f / (1.f + __expf(-x)); }

__device__ inline float bf2f(u16 u) {
  union { unsigned int i; float f; } v; v.i = ((unsigned int)u) << 16; return v.f;
}
__device__ inline u16 f2bf(float f) {
  union { float f; unsigned int i; } v; v.f = f;
  unsigned int r = v.i + 0x7FFFu + ((v.i >> 16) & 1u);  // RNE
  return (u16)(r >> 16);
}

// ---------- degree pipeline ----------
__global__ void k_init(float* deg, int* cursor, int n) {
  int i = blockIdx.x * blockDim.x + threadIdx.x;
  if (i < n) { deg[i] = 1.0f; cursor[i] = 0; }
}
__global__ void k_edge_deg(const void* __restrict__ ei, ll E, float* deg) {
  ll i = (ll)blockIdx.x * blockDim.x + threadIdx.x;
  if (i >= E) return;
  bool is64 = ei_is64(ei);
  atomicAdd(&deg[ei_at(ei, E + i, is64)], 1.0f);
}
__global__ void k_fin_deg(const float* __restrict__ deg, float* __restrict__ isd,
                          float* __restrict__ invd, int n) {
  int i = blockIdx.x * blockDim.x + threadIdx.x;
  if (i < n) {
    float d = deg[i];
    isd[i] = rsqrtf(d);
    invd[i] = 1.0f / d;
  }
}

// ---------- 3-kernel prefix scan over in-degrees ----------
__global__ __launch_bounds__(1024) void k_scan1(const float* __restrict__ deg,
                                                int* __restrict__ rowp,
                                                int* __restrict__ part, int n) {
  __shared__ int sm[1024];
  int b = blockIdx.x, tid = threadIdx.x;
  int i = b * 1024 + tid;
  int v = (i < n) ? ((int)deg[i] - 1) : 0;
  sm[tid] = v;
  __syncthreads();
  for (int off = 1; off < 1024; off <<= 1) {
    int t = (tid >= off) ? sm[tid - off] : 0;
    __syncthreads();
    sm[tid] += t;
    __syncthreads();
  }
  if (i < n) rowp[i + 1] = sm[tid];
  if (tid == 1023) part[b] = sm[1023];
}
__global__ void k_scan2(const int* __restrict__ part, int* __restrict__ offs, int nb) {
  __shared__ int sm[128];
  int t = threadIdx.x;
  int v = (t < nb) ? part[t] : 0;
  sm[t] = v;
  __syncthreads();
  for (int off = 1; off < 128; off <<= 1) {
    int u = (t >= off) ? sm[t - off] : 0;
    __syncthreads();
    sm[t] += u;
    __syncthreads();
  }
  offs[t] = sm[t] - v;  // exclusive
}
__global__ __launch_bounds__(1024) void k_scan3(int* __restrict__ rowp,
                                                const int* __restrict__ offs, int n) {
  int i = blockIdx.x * 1024 + threadIdx.x;
  if (i == 0) rowp[0] = 0;
  if (i < n) rowp[i + 1] += offs[blockIdx.x];
}

// ---------- CSR fill ----------
__global__ void k_fill(const void* __restrict__ ei, ll E,
                       const int* __restrict__ rowp, int* __restrict__ cursor,
                       int* __restrict__ col, float* __restrict__ w,
                       const float* __restrict__ isd) {
  ll i = (ll)blockIdx.x * blockDim.x + threadIdx.x;
  if (i >= E) return;
  bool is64 = ei_is64(ei);
  int s = ei_at(ei, i, is64);
  int d = ei_at(ei, E + i, is64);
  int pos = rowp[d] + atomicAdd(&cursor[d], 1);
  col[pos] = s;
  w[pos] = isd[s] * isd[d];
}

// ---------- weight transpose + bf16: Wt[n][k] = bf16(W[k][n]) ----------
__global__ void k_wt(const float* __restrict__ W, u16* __restrict__ Wt, int K, int N) {
  int t = blockIdx.x * blockDim.x + threadIdx.x;
  if (t >= K * N) return;
  int k = t % K, n = t / K;
  Wt[t] = f2bf(W[(size_t)k * N + n]);
}

// ---------- CSR gather aggregation, fused diag + optional bias/tanh ----------
// out[d, 0:F] = act( invd[d]*in[d,:] + sum_j w_j * in[col_j,:] + bias ); F = 4<<lgC
// EPI: 0 none, 1 tanh(v+bias).  OBF: 1 -> bf16 out, 0 -> fp32 out.
template <int EPI, int OBF>
__global__ void k_gather(const int* __restrict__ rowp, const int* __restrict__ col,
                         const float* __restrict__ w,
                         const float* __restrict__ in, int ldin,
                         const float* __restrict__ invd, const float* __restrict__ bias,
                         void* __restrict__ outv, int n, int lgC) {
  ll gid = (ll)blockIdx.x * blockDim.x + threadIdx.x;
  ll total = (ll)n << lgC;
  if (gid >= total) return;
  int d = (int)(gid >> lgC);
  int c4 = (int)(gid & ((1 << lgC) - 1));
  float4 acc;
  {
    float4 v = *(const float4*)(in + (size_t)d * ldin + c4 * 4);
    float s = invd[d];
    acc.x = v.x * s; acc.y = v.y * s; acc.z = v.z * s; acc.w = v.w * s;
  }
  int b = rowp[d], e = rowp[d + 1];
  for (int j = b; j < e; ++j) {
    int s = col[j];
    float wt = w[j];
    float4 v = *(const float4*)(in + (size_t)s * ldin + c4 * 4);
    acc.x += wt * v.x; acc.y += wt * v.y; acc.z += wt * v.z; acc.w += wt * v.w;
  }
  if (EPI == 1) {
    int c = c4 * 4;
    acc.x = fast_tanh(acc.x + bias[c + 0]);
    acc.y = fast_tanh(acc.y + bias[c + 1]);
    acc.z = fast_tanh(acc.z + bias[c + 2]);
    acc.w = fast_tanh(acc.w + bias[c + 3]);
  }
  if (OBF) {
    ushort4 o;
    o.x = f2bf(acc.x); o.y = f2bf(acc.y); o.z = f2bf(acc.z); o.w = f2bf(acc.w);
    ((ushort4*)outv)[gid] = o;
  } else {
    ((float4*)outv)[gid] = acc;
  }
}

// ---------- MFMA bf16 GEMM: C[M,Ncols] = A[M,K]bf16 @ Bt[Ncols,K]bf16 ----------
// Block = 4 waves stacked over rows: block tile 256 rows x 64 cols.
// grid = (Ncols/64, cdiv(M,256)).  Wave tile 64x64 via 4x4 frags of 16x16x32.
// CACC: 1 -> C += (fp32 RMW).  EPI: 1 -> tanh(v+bias[gc]).  OBF: 1 -> bf16 store.
template <int CACC, int EPI, int OBF>
__global__ __launch_bounds__(256) void k_mfma(const u16* __restrict__ A, int ldA,
                                              const u16* __restrict__ Bt, int ldB,
                                              const float* __restrict__ bias,
                                              void* __restrict__ Cv, int ldC,
                                              int M, int K) {
  const int lane = threadIdx.x & 63;
  const int wid = threadIdx.x >> 6;
  const int r0 = blockIdx.y * 256 + wid * 64;
  const int c0 = blockIdx.x * 64;
  const int lr = lane & 15;
  const int kb = (lane >> 4) * 8;

  f32x4 acc[4][4];
#pragma unroll
  for (int i = 0; i < 4; ++i)
#pragma unroll
    for (int j = 0; j < 4; ++j) acc[i][j] = (f32x4)0.f;

  const u16* ap[4];
#pragma unroll
  for (int fm = 0; fm < 4; ++fm) {
    int r = r0 + fm * 16 + lr;
    if (r > M - 1) r = M - 1;  // clamp tail rows (stores guarded)
    ap[fm] = A + (size_t)r * ldA + kb;
  }
  const u16* bp[4];
#pragma unroll
  for (int fn = 0; fn < 4; ++fn) {
    int c = c0 + fn * 16 + lr;
    bp[fn] = Bt + (size_t)c * ldB + kb;
  }

  for (int k0 = 0; k0 < K; k0 += 32) {
    bf16x8 a[4], b[4];
#pragma unroll
    for (int i = 0; i < 4; ++i) a[i] = *(const bf16x8*)(ap[i] + k0);
#pragma unroll
    for (int i = 0; i < 4; ++i) b[i] = *(const bf16x8*)(bp[i] + k0);
#pragma unroll
    for (int fm = 0; fm < 4; ++fm)
#pragma unroll
      for (int fn = 0; fn < 4; ++fn)
        acc[fm][fn] = __builtin_amdgcn_mfma_f32_16x16x32_bf16(a[fm], b[fn], acc[fm][fn], 0, 0, 0);
  }

  // C/D mapping: col = lane&15, row = (lane>>4)*4 + j (m89-verified)
  const int orow = (lane >> 4) * 4;
  const int ocol = lane & 15;
#pragma unroll
  for (int fm = 0; fm < 4; ++fm) {
#pragma unroll
    for (int j = 0; j < 4; ++j) {
      int gr = r0 + fm * 16 + orow + j;
      if (gr >= M) continue;
#pragma unroll
      for (int fn = 0; fn < 4; ++fn) {
        int gc = c0 + fn * 16 + ocol;
        float v = acc[fm][fn][j];
        size_t off = (size_t)gr * ldC + gc;
        if (CACC) v += ((const float*)Cv)[off];
        if (EPI == 1) v = fast_tanh(v + bias[gc]);
        if (OBF) ((u16*)Cv)[off] = f2bf(v);
        else     ((float*)Cv)[off] = v;
      }
    }
  }
}

// ---------- fp32 VALU GEMM (classifier only: N=100 tail) ----------
template <int EPI>
__global__ __launch_bounds__(256) void k_gemm(const float* __restrict__ A, int ldA,
                                              const float* __restrict__ B, int ldB,
                                              const float* __restrict__ bias,
                                              float* __restrict__ C, int ldC,
                                              int M, int N, int K) {
  const int BM = 128, BN = 64, BK = 16;
  __shared__ float As[BK][BM + 4];
  __shared__ float Bs[BK][BN];
  const int tid = threadIdx.x;
  const int tx = tid & 15, ty = tid >> 4;
  const int row0 = blockIdx.y * BM, col0 = blockIdx.x * BN;

  float acc[8][4] = {};

  for (int k0 = 0; k0 < K; k0 += BK) {
#pragma unroll
    for (int l = 0; l < 2; ++l) {
      int f = tid + l * 256;
      int r = f >> 2, kk = (f & 3) * 4;
      int gr = row0 + r;
      if (gr >= M) gr = M - 1;
      const float4 av = *(const float4*)(A + (size_t)gr * ldA + k0 + kk);
      As[kk + 0][r] = av.x;
      As[kk + 1][r] = av.y;
      As[kk + 2][r] = av.z;
      As[kk + 3][r] = av.w;
    }
    {
      int kr = tid >> 4, c = (tid & 15) * 4;
      int gc = col0 + c;
      const float* bp = B + (size_t)(k0 + kr) * ldB;
      float4 bv;
      if (gc + 3 < N) {
        bv = *(const float4*)(bp + gc);
      } else {
        bv.x = (gc + 0 < N) ? bp[gc + 0] : 0.f;
        bv.y = (gc + 1 < N) ? bp[gc + 1] : 0.f;
        bv.z = (gc + 2 < N) ? bp[gc + 2] : 0.f;
        bv.w = (gc + 3 < N) ? bp[gc + 3] : 0.f;
      }
      *(float4*)&Bs[kr][c] = bv;
    }
    __syncthreads();
#pragma unroll
    for (int k = 0; k < BK; ++k) {
      float a[8], b[4];
      *(float4*)&a[0] = *(const float4*)&As[k][ty * 8];
      *(float4*)&a[4] = *(const float4*)&As[k][ty * 8 + 4];
      *(float4*)&b[0] = *(const float4*)&Bs[k][tx * 4];
#pragma unroll
      for (int i = 0; i < 8; ++i)
#pragma unroll
        for (int j = 0; j < 4; ++j) acc[i][j] += a[i] * b[j];
    }
    __syncthreads();
  }

#pragma unroll
  for (int i = 0; i < 8; ++i) {
    int gr = row0 + ty * 8 + i;
    if (gr >= M) break;
#pragma unroll
    for (int j = 0; j < 4; ++j) {
      int gc = col0 + tx * 4 + j;
      if (gc >= N) continue;
      float v = acc[i][j];
      if (EPI == 2) v = fast_sigmoid(v + bias[gc]);
      C[(size_t)gr * ldC + gc] = v;
    }
  }
}

// ---------- launch ----------
static inline int cdiv(ll a, ll b) { return (int)((a + b - 1) / b); }

extern "C" void kernel_launch(void* const* d_in, const int* in_sizes, int n_in,
                              void* d_out, int out_size, void* d_ws, size_t ws_size,
                              hipStream_t stream) {
  const float* x  = (const float*)d_in[0];
  const void*  ei = d_in[1];
  const float* W1 = (const float*)d_in[2];
  const float* b1 = (const float*)d_in[3];
  const float* W2 = (const float*)d_in[4];
  const float* b2 = (const float*)d_in[5];
  const float* W3 = (const float*)d_in[6];
  const float* b3 = (const float*)d_in[7];
  const float* Wc = (const float*)d_in[8];
  const float* bc = (const float*)d_in[9];

  const int Nn = in_sizes[0] / 256;  // 100000
  const ll  E  = in_sizes[1] / 2;    // 400000

  // ===== d_ws: base 256.0 MB (proven): h1 bf16 [N,1024] | q3 fp32 [N,128].
  // Path A (ws_size >= 460.8 MB): + q2 fp32 [N,512] -> single-pass layer-2 GEMM.
  u16*   h1 = (u16*)d_ws;
  float* q3 = (float*)((char*)d_ws + (size_t)Nn * 2048);
  float* q2 = (float*)((char*)d_ws + (size_t)Nn * 2560);
  const bool bigws = (ws_size >= (size_t)Nn * 4608);

  // ===== d_out scratch (22.8M floats), liveness-scheduled (same map as round 5) =====
  float* ob     = (float*)d_out;
  float* deg    = ob;
  float* isd    = ob + Nn;
  float* invd   = ob + 2 * (size_t)Nn;
  int*   rowp   = (int*)(ob + 3 * (size_t)Nn);
  int*   cursor = (int*)(ob + 4 * (size_t)Nn + 4);
  int*   colx   = (int*)(ob + 5 * (size_t)Nn + 8);
  float* wgt    = ob + 5 * (size_t)Nn + 8 + E;
  int*   part   = (int*)(ob + 5 * (size_t)Nn + 8 + 2 * E);
  int*   offs   = part + 128;
  u16*   W1t    = (u16*)(offs + 128);                   // [1024][256]
  u16*   W2t    = W1t + 1024 * 256;                     // [512][1024]
  u16*   W3t    = W2t + 512 * 1024;                     // [128][512]
  float* stA    = ob + 1800000;                         // 12.8M floats
  u16*   stB    = (u16*)(ob + 14600000);                // 12.8M u16
  float* outf   = ob;                                   // [N,100]
  float* hout   = ob + (size_t)Nn * 100;                // [N,128]

  const int T = 256;
  const int GZ = cdiv(Nn, 256);   // MFMA grid rows (391)
  const int SB = cdiv(Nn, 1024);  // scan blocks (98)

  // ---- degrees + CSR + weight conversion ----
  k_init<<<cdiv(Nn, T), T, 0, stream>>>(deg, cursor, Nn);
  k_edge_deg<<<cdiv(E, T), T, 0, stream>>>(ei, E, deg);
  k_fin_deg<<<cdiv(Nn, T), T, 0, stream>>>(deg, isd, invd, Nn);
  k_scan1<<<SB, 1024, 0, stream>>>(deg, rowp, part, Nn);
  k_scan2<<<1, 128, 0, stream>>>(part, offs, SB);
  k_scan3<<<SB, 1024, 0, stream>>>(rowp, offs, Nn);
  k_fill<<<cdiv(E, T), T, 0, stream>>>(ei, E, rowp, cursor, colx, wgt, isd);
  k_wt<<<cdiv(256 * 1024, T), T, 0, stream>>>(W1, W1t, 256, 1024);
  k_wt<<<cdiv(1024 * 512, T), T, 0, stream>>>(W2, W2t, 1024, 512);
  k_wt<<<cdiv(512 * 128, T), T, 0, stream>>>(W3, W3t, 512, 128);

  // ---- layer 1: Sx = S x (bf16), h1 = tanh(Sx @ W1 + b1) (bf16, MFMA) ----
  {
    ll t4 = (ll)Nn * 64;  // F=256
    k_gather<0, 1><<<cdiv(t4, T), T, 0, stream>>>(rowp, colx, wgt, x, 256, invd,
                                                  nullptr, stA, Nn, 6);
    dim3 g(16, GZ);
    k_mfma<0, 1, 1><<<g, T, 0, stream>>>((const u16*)stA, 256, W1t, 256, b1,
                                         h1, 1024, Nn, 256);
  }

  // ---- layer 2 (+ fused layer-3 GEMM) ----
  if (bigws) {
    // Path A: q2 = h1 @ W2 in ONE pass (h1 read once; L3 catches cross-column reuse)
    dim3 g(8, GZ);
    k_mfma<0, 0, 0><<<g, T, 0, stream>>>(h1, 1024, W2t, 1024, nullptr,
                                         q2, 512, Nn, 1024);
    for (int c = 0; c < 4; ++c) {
      const int c0 = c * 128;
      ll t4 = (ll)Nn * 32;
      k_gather<1, 1><<<cdiv(t4, T), T, 0, stream>>>(rowp, colx, wgt, q2 + c0, 512, invd,
                                                    b2 + c0, stB, Nn, 5);
      dim3 gp(2, GZ);
      if (c == 0)
        k_mfma<0, 0, 0><<<gp, T, 0, stream>>>(stB, 128, W3t + c0, 512,
                                              nullptr, q3, 128, Nn, 128);
      else
        k_mfma<1, 0, 0><<<gp, T, 0, stream>>>(stB, 128, W3t + c0, 512,
                                              nullptr, q3, 128, Nn, 128);
    }
  } else {
    // Path B: 4 col-chunks (h1 streamed 4x) — round-5 flow
    for (int c = 0; c < 4; ++c) {
      const int c0 = c * 128;
      {
        dim3 g(2, GZ);
        k_mfma<0, 0, 0><<<g, T, 0, stream>>>(h1, 1024, W2t + (size_t)c0 * 1024, 1024,
                                             nullptr, stA, 128, Nn, 1024);
      }
      ll t4 = (ll)Nn * 32;
      k_gather<1, 1><<<cdiv(t4, T), T, 0, stream>>>(rowp, colx, wgt, stA, 128, invd,
                                                    b2 + c0, stB, Nn, 5);
      {
        dim3 g(2, GZ);
        if (c == 0)
          k_mfma<0, 0, 0><<<g, T, 0, stream>>>(stB, 128, W3t + c0, 512,
                                               nullptr, q3, 128, Nn, 128);
        else
          k_mfma<1, 0, 0><<<g, T, 0, stream>>>(stB, 128, W3t + c0, 512,
                                               nullptr, q3, 128, Nn, 128);
      }
    }
  }

  // ---- layer 3 aggregation: h3 = tanh(S q3 + b3) -> hout (fp32) ----
  {
    ll t4 = (ll)Nn * 32;
    k_gather<1, 0><<<cdiv(t4, T), T, 0, stream>>>(rowp, colx, wgt, q3, 128, invd,
                                                  b3, hout, Nn, 5);
  }

  // ---- classifier: out = sigmoid(h3 @ Wc + bc) (fp32 VALU, N=100 tail) ----
  {
    dim3 g(cdiv(100, 64), cdiv(Nn, 128));
    k_gemm<2><<<g, T, 0, stream>>>(hout, 128, Wc, 100, bc, outf, 100, Nn, 100, 128);
  }
}